// Round 4
// baseline (717.641 us; speedup 1.0000x reference)
//
#include <hip/hip_runtime.h>
#include <hip/hip_bf16.h>
#include <math.h>

#define D 128
#define BIN_CHUNK 4096
#define BIN_CAP 56
#define NBUCK_MAX 128

typedef __attribute__((ext_vector_type(8))) short bf16x8;
typedef __attribute__((ext_vector_type(4))) float f32x4;

static __device__ __forceinline__ unsigned short f2b(float f) {
  __hip_bfloat16 h = __float2bfloat16(f);
  return *reinterpret_cast<unsigned short*>(&h);
}
static __device__ __forceinline__ float blo(unsigned u) { return __uint_as_float(u << 16); }
static __device__ __forceinline__ float bhi(unsigned u) { return __uint_as_float(u & 0xffff0000u); }

// ---------------- CSR build ----------------
__global__ __launch_bounds__(256) void zero_ints(int* __restrict__ p, int n) {
  int i = blockIdx.x * 256 + threadIdx.x;
  if (i < n) p[i] = 0;
}

__global__ __launch_bounds__(256) void hist_kernel(const int* __restrict__ rows, int* __restrict__ counts, int E) {
  int e = blockIdx.x * 256 + threadIdx.x;
  if (e < E) atomicAdd(&counts[rows[e]], 1);
}

__global__ __launch_bounds__(256) void blocksum_kernel(const int* __restrict__ counts, int* __restrict__ bsums, int N) {
  int b = blockIdx.x, t = threadIdx.x;
  int base = b * 1024 + t * 4;
  int s = 0;
#pragma unroll
  for (int q = 0; q < 4; ++q) { int i = base + q; if (i < N) s += counts[i]; }
  for (int off = 32; off; off >>= 1) s += __shfl_xor(s, off);
  __shared__ int wsum[4];
  int w = t >> 6, lane = t & 63;
  if (lane == 0) wsum[w] = s;
  __syncthreads();
  if (t == 0) bsums[b] = wsum[0] + wsum[1] + wsum[2] + wsum[3];
}

__global__ __launch_bounds__(128) void scan_bsums(const int* __restrict__ bsums, int* __restrict__ bpref, int NB) {
  int t = threadIdx.x;
  __shared__ int s[128];
  int v = (t < NB) ? bsums[t] : 0;
  s[t] = v;
  __syncthreads();
  for (int d = 1; d < 128; d <<= 1) {
    int x = (t >= d) ? s[t - d] : 0;
    __syncthreads();
    s[t] += x;
    __syncthreads();
  }
  if (t < NB) bpref[t] = s[t] - v;
}

__global__ __launch_bounds__(256) void scan_kernel(const int* __restrict__ counts, const int* __restrict__ bpref,
                                                   int* __restrict__ offsets, int* __restrict__ cursor, int N, int E) {
  int b = blockIdx.x, t = threadIdx.x;
  int base = b * 1024 + t * 4;
  int c[4]; int tsum = 0;
#pragma unroll
  for (int q = 0; q < 4; ++q) { int i = base + q; c[q] = (i < N) ? counts[i] : 0; tsum += c[q]; }
  __shared__ int s[256];
  s[t] = tsum;
  __syncthreads();
  for (int d = 1; d < 256; d <<= 1) {
    int x = (t >= d) ? s[t - d] : 0;
    __syncthreads();
    s[t] += x;
    __syncthreads();
  }
  int run = bpref[b] + s[t] - tsum;
#pragma unroll
  for (int q = 0; q < 4; ++q) {
    int i = base + q;
    if (i < N) { offsets[i] = run; cursor[i] = run; }
    run += c[q];
  }
  if (b == 0 && t == 0) offsets[N] = E;
}

__global__ __launch_bounds__(256) void init_gcur(const int* __restrict__ offsets, int* __restrict__ gcur,
                                                 int NBUCK, int bshift, int N) {
  int b = blockIdx.x * 256 + threadIdx.x;
  if (b < NBUCK) {
    int r = b << bshift;
    gcur[b] = offsets[r < N ? r : N];
  }
}

// Pass B: bin edges into coarse buckets with LDS staging; coalesced bucket appends.
// entry: .x = (row_lo << 17) | col, .y = val bits
__global__ __launch_bounds__(256) void bin_kernel(const int* __restrict__ rows, const int* __restrict__ cols,
                                                  const float* __restrict__ vals, int* __restrict__ gcur,
                                                  uint2* __restrict__ gbin, int E, int NBUCK, int bshift) {
  __shared__ unsigned lcnt[NBUCK_MAX];
  __shared__ uint2 lbuf[NBUCK_MAX][BIN_CAP];
  int tid = threadIdx.x;
  if (tid < NBUCK_MAX) lcnt[tid] = 0;
  __syncthreads();
  int base_e = blockIdx.x * BIN_CHUNK;
  unsigned rmask = (1u << bshift) - 1u;
#pragma unroll
  for (int it = 0; it < BIN_CHUNK / 256; ++it) {
    int e = base_e + it * 256 + tid;
    if (e < E) {
      unsigned r = (unsigned)rows[e];
      unsigned c = (unsigned)cols[e];
      unsigned v = __float_as_uint(vals[e]);
      int b = r >> bshift;
      uint2 en = make_uint2(((r & rmask) << 17) | c, v);
      unsigned pos = atomicAdd(&lcnt[b], 1u);
      if (pos < BIN_CAP) lbuf[b][pos] = en;
      else { int gp = atomicAdd(&gcur[b], 1); gbin[gp] = en; }  // rare overflow
    }
  }
  __syncthreads();
  int wv = tid >> 6, ln = tid & 63;
  for (int b = wv; b < NBUCK; b += 4) {
    int c = (int)lcnt[b];
    if (c > BIN_CAP) c = BIN_CAP;
    if (c == 0) continue;
    int gbase = 0;
    if (ln == 0) gbase = atomicAdd(&gcur[b], c);
    gbase = __shfl(gbase, 0);
    if (ln < c) gbin[gbase + ln] = lbuf[b][ln];
  }
}

// Pass C: per-bucket scatter into final CSR (writes stay within ~L2-resident region)
__global__ __launch_bounds__(256) void debin_kernel(const uint2* __restrict__ gbin, const int* __restrict__ offsets,
                                                    int* __restrict__ cursor, uint2* __restrict__ ep,
                                                    int N, int bshift) {
  int b = blockIdx.x;
  int r0 = b << bshift;
  int r1 = (b + 1) << bshift;
  if (r1 > N) r1 = N;
  int s = offsets[r0 < N ? r0 : N];
  int e = offsets[r1];
  for (int i = s + threadIdx.x; i < e; i += 256) {
    uint2 en = gbin[i];
    int r = r0 + (int)(en.x >> 17);
    unsigned col = en.x & 0x1FFFFu;
    int pos = atomicAdd(&cursor[r], 1);
    ep[pos] = make_uint2(col, en.y);
  }
}

// ---------------- fp32 -> bf16 converters ----------------
__global__ __launch_bounds__(256) void conv_bf16(const float* __restrict__ in, unsigned short* __restrict__ outv, int n8) {
  int t = blockIdx.x * 256 + threadIdx.x;
  if (t >= n8) return;
  size_t base = (size_t)t * 8;
  float4 a = *(const float4*)&in[base];
  float4 b = *(const float4*)&in[base + 4];
  ushort4 o0, o1;
  o0.x = f2b(a.x); o0.y = f2b(a.y); o0.z = f2b(a.z); o0.w = f2b(a.w);
  o1.x = f2b(b.x); o1.y = f2b(b.y); o1.z = f2b(b.z); o1.w = f2b(b.w);
  *(ushort4*)&outv[base] = o0;
  *(ushort4*)&outv[base + 4] = o1;
}

// ---------------- GEMM (MFMA bf16): Y[r][c] = sum_k X[r][k] * Wl[c][k] ----------------
__global__ __launch_bounds__(256) void gemm_mfma(const unsigned short* __restrict__ xb,
                                                 const unsigned short* __restrict__ wb,
                                                 unsigned short* __restrict__ Y, int N) {
  int wave = threadIdx.x >> 6, lane = threadIdx.x & 63;
  int bid = blockIdx.x;
  int ch = bid & 1, rblk = bid >> 1;
  int r0 = rblk * 64 + wave * 16;
  if (r0 >= N) return;
  int c0 = ch * 64;
  int lr = lane & 15, lk = lane >> 4;
  const unsigned short* xrow = xb + (size_t)(r0 + lr) * D + lk * 8;
  bf16x8 xf[4];
#pragma unroll
  for (int s = 0; s < 4; ++s) xf[s] = *(const bf16x8*)(xrow + 32 * s);
  f32x4 acc[4];
#pragma unroll
  for (int mt = 0; mt < 4; ++mt) acc[mt] = (f32x4){0.f, 0.f, 0.f, 0.f};
#pragma unroll
  for (int mt = 0; mt < 4; ++mt) {
    const unsigned short* wrow = wb + (size_t)(c0 + mt * 16 + lr) * D + lk * 8;
#pragma unroll
    for (int s = 0; s < 4; ++s) {
      bf16x8 wf = *(const bf16x8*)(wrow + 32 * s);
      acc[mt] = __builtin_amdgcn_mfma_f32_16x16x32_bf16(wf, xf[s], acc[mt], 0, 0, 0);
    }
  }
#pragma unroll
  for (int mt = 0; mt < 4; ++mt) {
    ushort4 o;
    o.x = f2b(acc[mt][0]); o.y = f2b(acc[mt][1]); o.z = f2b(acc[mt][2]); o.w = f2b(acc[mt][3]);
    *(ushort4*)&Y[(size_t)(r0 + lr) * D + c0 + mt * 16 + lk * 4] = o;
  }
}

// ---------------- SpMM + ReLU -> bf16 Xn + row norm ----------------
__global__ __launch_bounds__(256) void spmm_kernel(const uint4* __restrict__ Y, const int* __restrict__ offs,
                                                   const uint2* __restrict__ ep,
                                                   unsigned short* __restrict__ Xn, float* __restrict__ nrm, int N) {
  int w = threadIdx.x >> 6, lane = threadIdx.x & 63;
  int r = blockIdx.x * 4 + w;
  if (r >= N) return;
  int g = lane >> 4, l = lane & 15;
  int s = offs[r], e = offs[r + 1];
  float acc[8];
#pragma unroll
  for (int k = 0; k < 8; ++k) acc[k] = 0.f;
  for (int base = s; base < e; base += 16) {
    uint2 ed[4];
#pragma unroll
    for (int q = 0; q < 4; ++q) {
      int i = base + 4 * q + g;
      ed[q] = (i < e) ? ep[i] : make_uint2(0u, 0u);
    }
    uint4 yv[4];
#pragma unroll
    for (int q = 0; q < 4; ++q) yv[q] = Y[(size_t)ed[q].x * 16 + l];
#pragma unroll
    for (int q = 0; q < 4; ++q) {
      float f = __uint_as_float(ed[q].y);
      unsigned uu[4] = {yv[q].x, yv[q].y, yv[q].z, yv[q].w};
#pragma unroll
      for (int k = 0; k < 4; ++k) {
        acc[2 * k]     = fmaf(f, blo(uu[k]), acc[2 * k]);
        acc[2 * k + 1] = fmaf(f, bhi(uu[k]), acc[2 * k + 1]);
      }
    }
  }
#pragma unroll
  for (int k = 0; k < 8; ++k) {
    float a = acc[k];
    a += __shfl_xor(a, 16);
    a += __shfl_xor(a, 32);
    acc[k] = fmaxf(a, 0.f);
  }
  float ss = 0.f;
#pragma unroll
  for (int k = 0; k < 8; ++k) ss += acc[k] * acc[k];
  ss += __shfl_xor(ss, 1);
  ss += __shfl_xor(ss, 2);
  ss += __shfl_xor(ss, 4);
  ss += __shfl_xor(ss, 8);
  if (lane == 0) nrm[r] = sqrtf(ss);
  if (g == 0) {
    ushort4 o0, o1;
    o0.x = f2b(acc[0]); o0.y = f2b(acc[1]); o0.z = f2b(acc[2]); o0.w = f2b(acc[3]);
    o1.x = f2b(acc[4]); o1.y = f2b(acc[5]); o1.z = f2b(acc[6]); o1.w = f2b(acc[7]);
    size_t p = (size_t)r * D + l * 8;
    *(ushort4*)&Xn[p] = o0;
    *(ushort4*)&Xn[p + 4] = o1;
  }
}

// ---------------- final combine ----------------
__global__ __launch_bounds__(256) void combine_kernel(const float* __restrict__ emb,
                                                      const unsigned short* __restrict__ x1,
                                                      const unsigned short* __restrict__ x2,
                                                      const unsigned short* __restrict__ x3,
                                                      const float* __restrict__ nrm,
                                                      float* __restrict__ out, int N, float scl) {
  int w = threadIdx.x >> 6, lane = threadIdx.x & 63;
  int r = blockIdx.x * 4 + w;
  if (r >= N) return;
  size_t p = (size_t)r * D + 2 * lane;
  float2 v = *(const float2*)&emb[p];
  float ss = v.x * v.x + v.y * v.y;
  for (int off = 32; off; off >>= 1) ss += __shfl_xor(ss, off);
  float s0 = scl / fmaxf(sqrtf(ss), 1e-12f);
  float i1 = scl / fmaxf(nrm[r], 1e-12f);
  float i2 = scl / fmaxf(nrm[N + r], 1e-12f);
  float i3 = scl / fmaxf(nrm[2 * N + r], 1e-12f);
  unsigned a1 = *(const unsigned*)&x1[p];
  unsigned a2 = *(const unsigned*)&x2[p];
  unsigned a3 = *(const unsigned*)&x3[p];
  float2 o;
  o.x = s0 * v.x + i1 * blo(a1) + i2 * blo(a2) + i3 * blo(a3);
  o.y = s0 * v.y + i1 * bhi(a1) + i2 * bhi(a2) + i3 * bhi(a3);
  *(float2*)&out[p] = o;
}

// ---------------- launch ----------------
extern "C" void kernel_launch(void* const* d_in, const int* in_sizes, int n_in,
                              void* d_out, int out_size, void* d_ws, size_t ws_size,
                              hipStream_t stream) {
  const int* rows = (const int*)d_in[0];
  const int* cols = (const int*)d_in[1];
  const float* vals = (const float*)d_in[2];
  const float* emb = (const float*)d_in[3];
  const float* W = (const float*)d_in[4];
  float* out = (float*)d_out;

  int E = in_sizes[0];
  int N = in_sizes[3] / D;
  int L = in_sizes[4] / (D * D);
  float scl = 1.0f / (float)(L + 1);

  // bucket geometry: <=128 buckets, row_lo fits 15 bits (N <= 4.2M), col fits 17 bits (N <= 131072)
  int bshift = 10;
  while (((N + (1 << bshift) - 1) >> bshift) > NBUCK_MAX) bshift++;
  int NBUCK = (N + (1 << bshift) - 1) >> bshift;

  char* ws = (char*)d_ws;
  size_t off = 0;
  auto take = [&](size_t bytes) -> void* {
    void* p = ws + off;
    off += (bytes + 255) & ~(size_t)255;
    return p;
  };
  unsigned short* xb0 = (unsigned short*)take((size_t)N * D * 2);
  unsigned short* xb1 = (unsigned short*)take((size_t)N * D * 2);
  unsigned short* xb2 = (unsigned short*)take((size_t)N * D * 2);
  unsigned short* xb3 = (unsigned short*)take((size_t)N * D * 2);
  unsigned short* yB  = (unsigned short*)take((size_t)N * D * 2);
  unsigned short* wb  = (unsigned short*)take((size_t)L * D * D * 2);
  float* nrm = (float*)take((size_t)L * N * sizeof(float));
  int* counts = (int*)take((size_t)(N + 1) * 4);
  int* offsets = (int*)take((size_t)(N + 1) * 4);
  int* cursor = (int*)take((size_t)N * 4);
  int* bsums = (int*)take(512 * 4);
  int* bpref = (int*)take(512 * 4);
  int* gcur = (int*)take((size_t)NBUCK_MAX * 4);
  uint2* ep = (uint2*)take((size_t)E * 8);
  // gbin aliases xb1: used strictly before spmm layer 0 writes xb1 (stream-ordered)
  uint2* gbin = (uint2*)xb1;

  int NB = (N + 1023) / 1024;

  // CSR build
  zero_ints<<<(N + 256) / 256, 256, 0, stream>>>(counts, N + 1);
  hist_kernel<<<(E + 255) / 256, 256, 0, stream>>>(rows, counts, E);
  blocksum_kernel<<<NB, 256, 0, stream>>>(counts, bsums, N);
  scan_bsums<<<1, 128, 0, stream>>>(bsums, bpref, NB);
  scan_kernel<<<NB, 256, 0, stream>>>(counts, bpref, offsets, cursor, N, E);
  init_gcur<<<(NBUCK + 255) / 256, 256, 0, stream>>>(offsets, gcur, NBUCK, bshift, N);
  bin_kernel<<<(E + BIN_CHUNK - 1) / BIN_CHUNK, 256, 0, stream>>>(rows, cols, vals, gcur, gbin, E, NBUCK, bshift);
  debin_kernel<<<NBUCK, 256, 0, stream>>>(gbin, offsets, cursor, ep, N, bshift);

  // bf16 conversions
  int n8x = N * D / 8;
  conv_bf16<<<(n8x + 255) / 256, 256, 0, stream>>>(emb, xb0, n8x);
  int n8w = L * D * D / 8;
  conv_bf16<<<(n8w + 255) / 256, 256, 0, stream>>>(W, wb, n8w);

  unsigned short* xbufs[4] = {xb0, xb1, xb2, xb3};
  int nrb = (N + 63) / 64;
  for (int l = 0; l < L; ++l) {
    gemm_mfma<<<nrb * 2, 256, 0, stream>>>(xbufs[l], wb + (size_t)l * D * D, yB, N);
    spmm_kernel<<<(N + 3) / 4, 256, 0, stream>>>((const uint4*)yB, offsets, ep, xbufs[l + 1], nrm + (size_t)l * N, N);
  }
  combine_kernel<<<(N + 3) / 4, 256, 0, stream>>>(emb, xb1, xb2, xb3, nrm, out, N, scl);
}

// Round 5
// 502.605 us; speedup vs baseline: 1.4278x; 1.4278x over previous
//
#include <hip/hip_runtime.h>
#include <hip/hip_bf16.h>
#include <math.h>

#define D 128
#define NBUCK_MAX 128

typedef __attribute__((ext_vector_type(8))) short bf16x8;
typedef __attribute__((ext_vector_type(4))) float f32x4;

static __device__ __forceinline__ unsigned short f2b(float f) {
  __hip_bfloat16 h = __float2bfloat16(f);
  return *reinterpret_cast<unsigned short*>(&h);
}
static __device__ __forceinline__ float blo(unsigned u) { return __uint_as_float(u << 16); }
static __device__ __forceinline__ float bhi(unsigned u) { return __uint_as_float(u & 0xffff0000u); }

// ---------------- CSR build ----------------
__global__ __launch_bounds__(256) void zero_ints(int* __restrict__ p, int n) {
  int i = blockIdx.x * 256 + threadIdx.x;
  if (i < n) p[i] = 0;
}

__global__ __launch_bounds__(256) void hist_kernel(const int* __restrict__ rows, int* __restrict__ counts, int E) {
  int e = blockIdx.x * 256 + threadIdx.x;
  if (e < E) atomicAdd(&counts[rows[e]], 1);
}

__global__ __launch_bounds__(256) void blocksum_kernel(const int* __restrict__ counts, int* __restrict__ bsums, int N) {
  int b = blockIdx.x, t = threadIdx.x;
  int base = b * 1024 + t * 4;
  int s = 0;
#pragma unroll
  for (int q = 0; q < 4; ++q) { int i = base + q; if (i < N) s += counts[i]; }
  for (int off = 32; off; off >>= 1) s += __shfl_xor(s, off);
  __shared__ int wsum[4];
  int w = t >> 6, lane = t & 63;
  if (lane == 0) wsum[w] = s;
  __syncthreads();
  if (t == 0) bsums[b] = wsum[0] + wsum[1] + wsum[2] + wsum[3];
}

__global__ __launch_bounds__(128) void scan_bsums(const int* __restrict__ bsums, int* __restrict__ bpref, int NB) {
  int t = threadIdx.x;
  __shared__ int s[128];
  int v = (t < NB) ? bsums[t] : 0;
  s[t] = v;
  __syncthreads();
  for (int d = 1; d < 128; d <<= 1) {
    int x = (t >= d) ? s[t - d] : 0;
    __syncthreads();
    s[t] += x;
    __syncthreads();
  }
  if (t < NB) bpref[t] = s[t] - v;
}

__global__ __launch_bounds__(256) void scan_kernel(const int* __restrict__ counts, const int* __restrict__ bpref,
                                                   int* __restrict__ offsets, int* __restrict__ cursor, int N, int E) {
  int b = blockIdx.x, t = threadIdx.x;
  int base = b * 1024 + t * 4;
  int c[4]; int tsum = 0;
#pragma unroll
  for (int q = 0; q < 4; ++q) { int i = base + q; c[q] = (i < N) ? counts[i] : 0; tsum += c[q]; }
  __shared__ int s[256];
  s[t] = tsum;
  __syncthreads();
  for (int d = 1; d < 256; d <<= 1) {
    int x = (t >= d) ? s[t - d] : 0;
    __syncthreads();
    s[t] += x;
    __syncthreads();
  }
  int run = bpref[b] + s[t] - tsum;
#pragma unroll
  for (int q = 0; q < 4; ++q) {
    int i = base + q;
    if (i < N) { offsets[i] = run; cursor[i] = run; }
    run += c[q];
  }
  if (b == 0 && t == 0) offsets[N] = E;
}

// ---- radix partition by bucket (row >> bshift), WG-private histograms ----
// pass 1: per-WG bucket histogram (LDS = 128 ints only)
__global__ __launch_bounds__(256) void wg_hist(const int* __restrict__ rows, int* __restrict__ wghist,
                                               int E, int NW, int per, int bshift) {
  __shared__ int cnt[NBUCK_MAX];
  int tid = threadIdx.x, w = blockIdx.x;
  if (tid < NBUCK_MAX) cnt[tid] = 0;
  __syncthreads();
  int base = w * per;
  int end = base + per; if (end > E) end = E;
  for (int e = base + tid; e < end; e += 256) atomicAdd(&cnt[rows[e] >> bshift], 1);
  __syncthreads();
  if (tid < NBUCK_MAX) wghist[tid * NW + w] = cnt[tid];
}

// pass 2: scan WG-counts per bucket -> absolute start for each (bucket, wg)
__global__ __launch_bounds__(512) void scan_wg(const int* __restrict__ wghist, const int* __restrict__ offsets,
                                               int* __restrict__ wgstart, int NW, int bshift, int N) {
  int b = blockIdx.x, t = threadIdx.x;
  __shared__ int s[512];
  int v = (t < NW) ? wghist[b * NW + t] : 0;
  s[t] = v;
  __syncthreads();
  for (int d = 1; d < 512; d <<= 1) {
    int x = (t >= d) ? s[t - d] : 0;
    __syncthreads();
    s[t] += x;
    __syncthreads();
  }
  int r0 = b << bshift; if (r0 > N) r0 = N;
  if (t < NW) wgstart[b * NW + t] = offsets[r0] + s[t] - v;
}

// pass 3: write each edge directly to its final bucket segment (WG-private contiguous streams)
__global__ __launch_bounds__(256) void partition_kernel(const int* __restrict__ rows, const int* __restrict__ cols,
                                                        const float* __restrict__ vals, const int* __restrict__ wgstart,
                                                        uint2* __restrict__ gbin, int E, int NW, int per, int bshift) {
  __shared__ int cur[NBUCK_MAX];
  int tid = threadIdx.x, w = blockIdx.x;
  if (tid < NBUCK_MAX) cur[tid] = wgstart[tid * NW + w];
  __syncthreads();
  unsigned rmask = (1u << bshift) - 1u;
  int base = w * per;
  int end = base + per; if (end > E) end = E;
  for (int e = base + tid; e < end; e += 256) {
    unsigned r = (unsigned)rows[e];
    int b = r >> bshift;
    int pos = atomicAdd(&cur[b], 1);
    gbin[pos] = make_uint2(((r & rmask) << 17) | (unsigned)cols[e], __float_as_uint(vals[e]));
  }
}

// pass 4: per-bucket scatter into final CSR (writes stay within L2-resident ~131KB window)
__global__ __launch_bounds__(256) void debin_kernel(const uint2* __restrict__ gbin, const int* __restrict__ offsets,
                                                    int* __restrict__ cursor, uint2* __restrict__ ep,
                                                    int N, int bshift) {
  int b = blockIdx.x;
  int r0 = b << bshift;
  int r1 = (b + 1) << bshift;
  if (r1 > N) r1 = N;
  int s = offsets[r0 < N ? r0 : N];
  int e = offsets[r1];
  for (int i = s + threadIdx.x; i < e; i += 256) {
    uint2 en = gbin[i];
    int r = r0 + (int)(en.x >> 17);
    unsigned col = en.x & 0x1FFFFu;
    int pos = atomicAdd(&cursor[r], 1);
    ep[pos] = make_uint2(col, en.y);
  }
}

// ---------------- fp32 -> bf16 converters ----------------
__global__ __launch_bounds__(256) void conv_bf16(const float* __restrict__ in, unsigned short* __restrict__ outv, int n8) {
  int t = blockIdx.x * 256 + threadIdx.x;
  if (t >= n8) return;
  size_t base = (size_t)t * 8;
  float4 a = *(const float4*)&in[base];
  float4 b = *(const float4*)&in[base + 4];
  ushort4 o0, o1;
  o0.x = f2b(a.x); o0.y = f2b(a.y); o0.z = f2b(a.z); o0.w = f2b(a.w);
  o1.x = f2b(b.x); o1.y = f2b(b.y); o1.z = f2b(b.z); o1.w = f2b(b.w);
  *(ushort4*)&outv[base] = o0;
  *(ushort4*)&outv[base + 4] = o1;
}

// ---------------- GEMM (MFMA bf16): Y[r][c] = sum_k X[r][k] * Wl[c][k] ----------------
__global__ __launch_bounds__(256) void gemm_mfma(const unsigned short* __restrict__ xb,
                                                 const unsigned short* __restrict__ wb,
                                                 unsigned short* __restrict__ Y, int N) {
  int wave = threadIdx.x >> 6, lane = threadIdx.x & 63;
  int bid = blockIdx.x;
  int ch = bid & 1, rblk = bid >> 1;
  int r0 = rblk * 64 + wave * 16;
  if (r0 >= N) return;
  int c0 = ch * 64;
  int lr = lane & 15, lk = lane >> 4;
  const unsigned short* xrow = xb + (size_t)(r0 + lr) * D + lk * 8;
  bf16x8 xf[4];
#pragma unroll
  for (int s = 0; s < 4; ++s) xf[s] = *(const bf16x8*)(xrow + 32 * s);
  f32x4 acc[4];
#pragma unroll
  for (int mt = 0; mt < 4; ++mt) acc[mt] = (f32x4){0.f, 0.f, 0.f, 0.f};
#pragma unroll
  for (int mt = 0; mt < 4; ++mt) {
    const unsigned short* wrow = wb + (size_t)(c0 + mt * 16 + lr) * D + lk * 8;
#pragma unroll
    for (int s = 0; s < 4; ++s) {
      bf16x8 wf = *(const bf16x8*)(wrow + 32 * s);
      acc[mt] = __builtin_amdgcn_mfma_f32_16x16x32_bf16(wf, xf[s], acc[mt], 0, 0, 0);
    }
  }
#pragma unroll
  for (int mt = 0; mt < 4; ++mt) {
    ushort4 o;
    o.x = f2b(acc[mt][0]); o.y = f2b(acc[mt][1]); o.z = f2b(acc[mt][2]); o.w = f2b(acc[mt][3]);
    *(ushort4*)&Y[(size_t)(r0 + lr) * D + c0 + mt * 16 + lk * 4] = o;
  }
}

// ---------------- SpMM + ReLU -> bf16 Xn + row norm ----------------
__global__ __launch_bounds__(256) void spmm_kernel(const uint4* __restrict__ Y, const int* __restrict__ offs,
                                                   const uint2* __restrict__ ep,
                                                   unsigned short* __restrict__ Xn, float* __restrict__ nrm, int N) {
  int w = threadIdx.x >> 6, lane = threadIdx.x & 63;
  int r = blockIdx.x * 4 + w;
  if (r >= N) return;
  int g = lane >> 4, l = lane & 15;
  int s = offs[r], e = offs[r + 1];
  float acc[8];
#pragma unroll
  for (int k = 0; k < 8; ++k) acc[k] = 0.f;
  for (int base = s; base < e; base += 16) {
    uint2 ed[4];
#pragma unroll
    for (int q = 0; q < 4; ++q) {
      int i = base + 4 * q + g;
      ed[q] = (i < e) ? ep[i] : make_uint2(0u, 0u);
    }
    uint4 yv[4];
#pragma unroll
    for (int q = 0; q < 4; ++q) yv[q] = Y[(size_t)ed[q].x * 16 + l];
#pragma unroll
    for (int q = 0; q < 4; ++q) {
      float f = __uint_as_float(ed[q].y);
      unsigned uu[4] = {yv[q].x, yv[q].y, yv[q].z, yv[q].w};
#pragma unroll
      for (int k = 0; k < 4; ++k) {
        acc[2 * k]     = fmaf(f, blo(uu[k]), acc[2 * k]);
        acc[2 * k + 1] = fmaf(f, bhi(uu[k]), acc[2 * k + 1]);
      }
    }
  }
#pragma unroll
  for (int k = 0; k < 8; ++k) {
    float a = acc[k];
    a += __shfl_xor(a, 16);
    a += __shfl_xor(a, 32);
    acc[k] = fmaxf(a, 0.f);
  }
  float ss = 0.f;
#pragma unroll
  for (int k = 0; k < 8; ++k) ss += acc[k] * acc[k];
  ss += __shfl_xor(ss, 1);
  ss += __shfl_xor(ss, 2);
  ss += __shfl_xor(ss, 4);
  ss += __shfl_xor(ss, 8);
  if (lane == 0) nrm[r] = sqrtf(ss);
  if (g == 0) {
    ushort4 o0, o1;
    o0.x = f2b(acc[0]); o0.y = f2b(acc[1]); o0.z = f2b(acc[2]); o0.w = f2b(acc[3]);
    o1.x = f2b(acc[4]); o1.y = f2b(acc[5]); o1.z = f2b(acc[6]); o1.w = f2b(acc[7]);
    size_t p = (size_t)r * D + l * 8;
    *(ushort4*)&Xn[p] = o0;
    *(ushort4*)&Xn[p + 4] = o1;
  }
}

// ---------------- final combine ----------------
__global__ __launch_bounds__(256) void combine_kernel(const float* __restrict__ emb,
                                                      const unsigned short* __restrict__ x1,
                                                      const unsigned short* __restrict__ x2,
                                                      const unsigned short* __restrict__ x3,
                                                      const float* __restrict__ nrm,
                                                      float* __restrict__ out, int N, float scl) {
  int w = threadIdx.x >> 6, lane = threadIdx.x & 63;
  int r = blockIdx.x * 4 + w;
  if (r >= N) return;
  size_t p = (size_t)r * D + 2 * lane;
  float2 v = *(const float2*)&emb[p];
  float ss = v.x * v.x + v.y * v.y;
  for (int off = 32; off; off >>= 1) ss += __shfl_xor(ss, off);
  float s0 = scl / fmaxf(sqrtf(ss), 1e-12f);
  float i1 = scl / fmaxf(nrm[r], 1e-12f);
  float i2 = scl / fmaxf(nrm[N + r], 1e-12f);
  float i3 = scl / fmaxf(nrm[2 * N + r], 1e-12f);
  unsigned a1 = *(const unsigned*)&x1[p];
  unsigned a2 = *(const unsigned*)&x2[p];
  unsigned a3 = *(const unsigned*)&x3[p];
  float2 o;
  o.x = s0 * v.x + i1 * blo(a1) + i2 * blo(a2) + i3 * blo(a3);
  o.y = s0 * v.y + i1 * bhi(a1) + i2 * bhi(a2) + i3 * bhi(a3);
  *(float2*)&out[p] = o;
}

// ---------------- launch ----------------
extern "C" void kernel_launch(void* const* d_in, const int* in_sizes, int n_in,
                              void* d_out, int out_size, void* d_ws, size_t ws_size,
                              hipStream_t stream) {
  const int* rows = (const int*)d_in[0];
  const int* cols = (const int*)d_in[1];
  const float* vals = (const float*)d_in[2];
  const float* emb = (const float*)d_in[3];
  const float* W = (const float*)d_in[4];
  float* out = (float*)d_out;

  int E = in_sizes[0];
  int N = in_sizes[3] / D;
  int L = in_sizes[4] / (D * D);
  float scl = 1.0f / (float)(L + 1);

  // bucket geometry: <=128 buckets; row_lo fits (32-17) bits => N <= 4.2M; col 17 bits => N <= 131072
  int bshift = 10;
  while (((N + (1 << bshift) - 1) >> bshift) > NBUCK_MAX) bshift++;
  int NBUCK = (N + (1 << bshift) - 1) >> bshift;

  // chunking for the partition: NW <= 512 WGs
  int per = 4096;
  while ((E + per - 1) / per > 512) per *= 2;
  int NW = (E + per - 1) / per;

  char* ws = (char*)d_ws;
  size_t off = 0;
  auto take = [&](size_t bytes) -> void* {
    void* p = ws + off;
    off += (bytes + 255) & ~(size_t)255;
    return p;
  };
  unsigned short* xb0 = (unsigned short*)take((size_t)N * D * 2);
  unsigned short* xb1 = (unsigned short*)take((size_t)N * D * 2);
  unsigned short* xb2 = (unsigned short*)take((size_t)N * D * 2);
  unsigned short* xb3 = (unsigned short*)take((size_t)N * D * 2);
  unsigned short* yB  = (unsigned short*)take((size_t)N * D * 2);
  unsigned short* wb  = (unsigned short*)take((size_t)L * D * D * 2);
  float* nrm = (float*)take((size_t)L * N * sizeof(float));
  int* counts = (int*)take((size_t)(N + 1) * 4);
  int* offsets = (int*)take((size_t)(N + 1) * 4);
  int* cursor = (int*)take((size_t)N * 4);
  int* bsums = (int*)take(512 * 4);
  int* bpref = (int*)take(512 * 4);
  int* wghist = (int*)take((size_t)NBUCK_MAX * NW * 4);
  int* wgstart = (int*)take((size_t)NBUCK_MAX * NW * 4);
  uint2* ep = (uint2*)take((size_t)E * 8);
  // gbin aliases xb1: consumed (debin) strictly before spmm layer 0 writes xb1 (stream-ordered)
  uint2* gbin = (uint2*)xb1;

  int NB = (N + 1023) / 1024;

  // row-level CSR offsets
  zero_ints<<<(N + 256) / 256, 256, 0, stream>>>(counts, N + 1);
  hist_kernel<<<(E + 255) / 256, 256, 0, stream>>>(rows, counts, E);
  blocksum_kernel<<<NB, 256, 0, stream>>>(counts, bsums, N);
  scan_bsums<<<1, 128, 0, stream>>>(bsums, bpref, NB);
  scan_kernel<<<NB, 256, 0, stream>>>(counts, bpref, offsets, cursor, N, E);
  // radix partition into buckets, then per-bucket scatter
  wg_hist<<<NW, 256, 0, stream>>>(rows, wghist, E, NW, per, bshift);
  scan_wg<<<NBUCK, 512, 0, stream>>>(wghist, offsets, wgstart, NW, bshift, N);
  partition_kernel<<<NW, 256, 0, stream>>>(rows, cols, vals, wgstart, gbin, E, NW, per, bshift);
  debin_kernel<<<NBUCK, 256, 0, stream>>>(gbin, offsets, cursor, ep, N, bshift);

  // bf16 conversions
  int n8x = N * D / 8;
  conv_bf16<<<(n8x + 255) / 256, 256, 0, stream>>>(emb, xb0, n8x);
  int n8w = L * D * D / 8;
  conv_bf16<<<(n8w + 255) / 256, 256, 0, stream>>>(W, wb, n8w);

  unsigned short* xbufs[4] = {xb0, xb1, xb2, xb3};
  int nrb = (N + 63) / 64;
  for (int l = 0; l < L; ++l) {
    gemm_mfma<<<nrb * 2, 256, 0, stream>>>(xbufs[l], wb + (size_t)l * D * D, yB, N);
    spmm_kernel<<<(N + 3) / 4, 256, 0, stream>>>((const uint4*)yB, offsets, ep, xbufs[l + 1], nrm + (size_t)l * N, N);
  }
  combine_kernel<<<(N + 3) / 4, 256, 0, stream>>>(emb, xb1, xb2, xb3, nrm, out, N, scl);
}

// Round 6
// 415.919 us; speedup vs baseline: 1.7254x; 1.2084x over previous
//
#include <hip/hip_runtime.h>
#include <hip/hip_fp16.h>
#include <math.h>

#define D 128
#define NBUCK_MAX 128
#define BROWS 1024   // rows per bucket (bshift=10); requires N <= 131072 (col packs in 17 bits)

typedef _Float16 f16x8 __attribute__((ext_vector_type(8)));
typedef __attribute__((ext_vector_type(4))) float f32x4;

static __device__ __forceinline__ unsigned short f2h(float f) {
  __half h = __float2half(f);
  return *reinterpret_cast<unsigned short*>(&h);
}
static __device__ __forceinline__ float hlo(unsigned u) {
  __half2 h = *reinterpret_cast<__half2*>(&u);
  return __low2float(h);
}
static __device__ __forceinline__ float hhi(unsigned u) {
  __half2 h = *reinterpret_cast<__half2*>(&u);
  return __high2float(h);
}

// ---- radix partition by bucket (row >> bshift), WG-private histograms ----
// pass 1: per-WG bucket histogram (LDS = 128 ints)
__global__ __launch_bounds__(256) void wg_hist(const int* __restrict__ rows, int* __restrict__ wghist,
                                               int E, int NW, int per, int bshift) {
  __shared__ int cnt[NBUCK_MAX];
  int tid = threadIdx.x, w = blockIdx.x;
  if (tid < NBUCK_MAX) cnt[tid] = 0;
  __syncthreads();
  int base = w * per;
  int end = base + per; if (end > E) end = E;
  for (int e = base + tid; e < end; e += 256) atomicAdd(&cnt[rows[e] >> bshift], 1);
  __syncthreads();
  if (tid < NBUCK_MAX) wghist[tid * NW + w] = cnt[tid];
}

// pass 2: per-bucket exclusive scan of WG counts (local, no base) + bucket totals
__global__ __launch_bounds__(512) void scan_wg(const int* __restrict__ wghist, int* __restrict__ wgstart,
                                               int* __restrict__ btot, int NW) {
  int b = blockIdx.x, t = threadIdx.x;
  __shared__ int s[512];
  int v = (t < NW) ? wghist[b * NW + t] : 0;
  s[t] = v;
  __syncthreads();
  for (int d = 1; d < 512; d <<= 1) {
    int x = (t >= d) ? s[t - d] : 0;
    __syncthreads();
    s[t] += x;
    __syncthreads();
  }
  if (t < NW) wgstart[b * NW + t] = s[t] - v;
  if (t == 511) btot[b] = s[511];
}

// pass 3: exclusive scan of bucket totals -> bucket starts; bstart[NBUCK] = E
__global__ __launch_bounds__(128) void scan_buckets(const int* __restrict__ btot, int* __restrict__ bstart, int NBUCK) {
  int t = threadIdx.x;
  __shared__ int s[128];
  int v = (t < NBUCK) ? btot[t] : 0;
  s[t] = v;
  __syncthreads();
  for (int d = 1; d < 128; d <<= 1) {
    int x = (t >= d) ? s[t - d] : 0;
    __syncthreads();
    s[t] += x;
    __syncthreads();
  }
  if (t < NBUCK) bstart[t] = s[t] - v;
  if (t == 127) bstart[NBUCK] = s[127];
}

// pass 4: write each edge directly to its final bucket segment (WG-private contiguous streams)
__global__ __launch_bounds__(256) void partition_kernel(const int* __restrict__ rows, const int* __restrict__ cols,
                                                        const float* __restrict__ vals, const int* __restrict__ wgstart,
                                                        const int* __restrict__ bstart,
                                                        uint2* __restrict__ gbin, int E, int NW, int per, int bshift) {
  __shared__ int cur[NBUCK_MAX];
  int tid = threadIdx.x, w = blockIdx.x;
  if (tid < NBUCK_MAX) cur[tid] = bstart[tid] + wgstart[tid * NW + w];
  __syncthreads();
  unsigned rmask = (1u << bshift) - 1u;
  int base = w * per;
  int end = base + per; if (end > E) end = E;
  for (int e = base + tid; e < end; e += 256) {
    unsigned r = (unsigned)rows[e];
    int b = r >> bshift;
    int pos = atomicAdd(&cur[b], 1);
    gbin[pos] = make_uint2(((r & rmask) << 17) | (unsigned)cols[e], __float_as_uint(vals[e]));
  }
}

// pass 5: per-bucket: LDS row-histogram + scan -> row offsets; scatter slice into final CSR ep
__global__ __launch_bounds__(256) void debin2(const uint2* __restrict__ gbin, const int* __restrict__ bstart,
                                              int* __restrict__ offsets, uint2* __restrict__ ep,
                                              int N, int E, int bshift, int NBUCK) {
  __shared__ int cnt[BROWS];
  __shared__ int sblk[256];
  int b = blockIdx.x, t = threadIdx.x;
  int r0 = b << bshift;
  int r1 = r0 + BROWS; if (r1 > N) r1 = N;
  int nr = r1 - r0;
  int s0 = bstart[b], e0 = bstart[b + 1];
#pragma unroll
  for (int q = 0; q < 4; ++q) cnt[t * 4 + q] = 0;
  __syncthreads();
  for (int i = s0 + t; i < e0; i += 256) atomicAdd(&cnt[gbin[i].x >> 17], 1);
  __syncthreads();
  int c[4]; int tsum = 0;
#pragma unroll
  for (int q = 0; q < 4; ++q) { c[q] = cnt[4 * t + q]; tsum += c[q]; }
  sblk[t] = tsum;
  __syncthreads();
  for (int d = 1; d < 256; d <<= 1) {
    int x = (t >= d) ? sblk[t - d] : 0;
    __syncthreads();
    sblk[t] += x;
    __syncthreads();
  }
  int run = s0 + sblk[t] - tsum;
#pragma unroll
  for (int q = 0; q < 4; ++q) {
    int j = 4 * t + q;
    if (j < nr) offsets[r0 + j] = run;
    cnt[j] = run;   // reuse as absolute cursor
    run += c[q];
  }
  __syncthreads();
  for (int i = s0 + t; i < e0; i += 256) {
    uint2 en = gbin[i];
    int lr = (int)(en.x >> 17);
    int pos = atomicAdd(&cnt[lr], 1);
    ep[pos] = make_uint2(en.x & 0x1FFFFu, en.y);
  }
  if (b == NBUCK - 1 && t == 0) offsets[N] = E;
}

// ---------------- fp32 -> fp16 converter ----------------
__global__ __launch_bounds__(256) void conv_f16(const float* __restrict__ in, unsigned short* __restrict__ outv, int n8) {
  int t = blockIdx.x * 256 + threadIdx.x;
  if (t >= n8) return;
  size_t base = (size_t)t * 8;
  float4 a = *(const float4*)&in[base];
  float4 b = *(const float4*)&in[base + 4];
  ushort4 o0, o1;
  o0.x = f2h(a.x); o0.y = f2h(a.y); o0.z = f2h(a.z); o0.w = f2h(a.w);
  o1.x = f2h(b.x); o1.y = f2h(b.y); o1.z = f2h(b.z); o1.w = f2h(b.w);
  *(ushort4*)&outv[base] = o0;
  *(ushort4*)&outv[base + 4] = o1;
}

// ---------------- GEMM (MFMA f16): Y[r][c] = sum_k X[r][k] * Wl[c][k] ----------------
__global__ __launch_bounds__(256) void gemm_mfma(const unsigned short* __restrict__ xb,
                                                 const unsigned short* __restrict__ wb,
                                                 unsigned short* __restrict__ Y, int N) {
  int wave = threadIdx.x >> 6, lane = threadIdx.x & 63;
  int bid = blockIdx.x;
  int ch = bid & 1, rblk = bid >> 1;
  int r0 = rblk * 64 + wave * 16;
  if (r0 >= N) return;
  int c0 = ch * 64;
  int lr = lane & 15, lk = lane >> 4;
  const unsigned short* xrow = xb + (size_t)(r0 + lr) * D + lk * 8;
  f16x8 xf[4];
#pragma unroll
  for (int s = 0; s < 4; ++s) xf[s] = *(const f16x8*)(xrow + 32 * s);
  f32x4 acc[4];
#pragma unroll
  for (int mt = 0; mt < 4; ++mt) acc[mt] = (f32x4){0.f, 0.f, 0.f, 0.f};
#pragma unroll
  for (int mt = 0; mt < 4; ++mt) {
    const unsigned short* wrow = wb + (size_t)(c0 + mt * 16 + lr) * D + lk * 8;
#pragma unroll
    for (int s = 0; s < 4; ++s) {
      f16x8 wf = *(const f16x8*)(wrow + 32 * s);
      acc[mt] = __builtin_amdgcn_mfma_f32_16x16x32_f16(wf, xf[s], acc[mt], 0, 0, 0);
    }
  }
#pragma unroll
  for (int mt = 0; mt < 4; ++mt) {
    ushort4 o;
    o.x = f2h(acc[mt][0]); o.y = f2h(acc[mt][1]); o.z = f2h(acc[mt][2]); o.w = f2h(acc[mt][3]);
    *(ushort4*)&Y[(size_t)(r0 + lr) * D + c0 + mt * 16 + lk * 4] = o;
  }
}

// ---------------- SpMM + ReLU -> fp16 Xn + row norm ----------------
__global__ __launch_bounds__(256) void spmm_kernel(const uint4* __restrict__ Y, const int* __restrict__ offs,
                                                   const uint2* __restrict__ ep,
                                                   unsigned short* __restrict__ Xn, float* __restrict__ nrm, int N) {
  int w = threadIdx.x >> 6, lane = threadIdx.x & 63;
  int r = blockIdx.x * 4 + w;
  if (r >= N) return;
  int g = lane >> 4, l = lane & 15;
  int s = offs[r], e = offs[r + 1];
  float acc[8];
#pragma unroll
  for (int k = 0; k < 8; ++k) acc[k] = 0.f;
  for (int base = s; base < e; base += 16) {
    uint2 ed[4];
#pragma unroll
    for (int q = 0; q < 4; ++q) {
      int i = base + 4 * q + g;
      ed[q] = (i < e) ? ep[i] : make_uint2(0u, 0u);
    }
    uint4 yv[4];
#pragma unroll
    for (int q = 0; q < 4; ++q) yv[q] = Y[(size_t)ed[q].x * 16 + l];
#pragma unroll
    for (int q = 0; q < 4; ++q) {
      float f = __uint_as_float(ed[q].y);
      unsigned uu[4] = {yv[q].x, yv[q].y, yv[q].z, yv[q].w};
#pragma unroll
      for (int k = 0; k < 4; ++k) {
        acc[2 * k]     = fmaf(f, hlo(uu[k]), acc[2 * k]);
        acc[2 * k + 1] = fmaf(f, hhi(uu[k]), acc[2 * k + 1]);
      }
    }
  }
#pragma unroll
  for (int k = 0; k < 8; ++k) {
    float a = acc[k];
    a += __shfl_xor(a, 16);
    a += __shfl_xor(a, 32);
    acc[k] = fmaxf(a, 0.f);
  }
  float ss = 0.f;
#pragma unroll
  for (int k = 0; k < 8; ++k) ss += acc[k] * acc[k];
  ss += __shfl_xor(ss, 1);
  ss += __shfl_xor(ss, 2);
  ss += __shfl_xor(ss, 4);
  ss += __shfl_xor(ss, 8);
  if (lane == 0) nrm[r] = sqrtf(ss);
  if (g == 0) {
    ushort4 o0, o1;
    o0.x = f2h(acc[0]); o0.y = f2h(acc[1]); o0.z = f2h(acc[2]); o0.w = f2h(acc[3]);
    o1.x = f2h(acc[4]); o1.y = f2h(acc[5]); o1.z = f2h(acc[6]); o1.w = f2h(acc[7]);
    size_t p = (size_t)r * D + l * 8;
    *(ushort4*)&Xn[p] = o0;
    *(ushort4*)&Xn[p + 4] = o1;
  }
}

// ---------------- final combine ----------------
__global__ __launch_bounds__(256) void combine_kernel(const float* __restrict__ emb,
                                                      const unsigned short* __restrict__ x1,
                                                      const unsigned short* __restrict__ x2,
                                                      const unsigned short* __restrict__ x3,
                                                      const float* __restrict__ nrm,
                                                      float* __restrict__ out, int N, float scl) {
  int w = threadIdx.x >> 6, lane = threadIdx.x & 63;
  int r = blockIdx.x * 4 + w;
  if (r >= N) return;
  size_t p = (size_t)r * D + 2 * lane;
  float2 v = *(const float2*)&emb[p];
  float ss = v.x * v.x + v.y * v.y;
  for (int off = 32; off; off >>= 1) ss += __shfl_xor(ss, off);
  float s0 = scl / fmaxf(sqrtf(ss), 1e-12f);
  float i1 = scl / fmaxf(nrm[r], 1e-12f);
  float i2 = scl / fmaxf(nrm[N + r], 1e-12f);
  float i3 = scl / fmaxf(nrm[2 * N + r], 1e-12f);
  unsigned a1 = *(const unsigned*)&x1[p];
  unsigned a2 = *(const unsigned*)&x2[p];
  unsigned a3 = *(const unsigned*)&x3[p];
  float2 o;
  o.x = s0 * v.x + i1 * hlo(a1) + i2 * hlo(a2) + i3 * hlo(a3);
  o.y = s0 * v.y + i1 * hhi(a1) + i2 * hhi(a2) + i3 * hhi(a3);
  *(float2*)&out[p] = o;
}

// ---------------- launch ----------------
extern "C" void kernel_launch(void* const* d_in, const int* in_sizes, int n_in,
                              void* d_out, int out_size, void* d_ws, size_t ws_size,
                              hipStream_t stream) {
  const int* rows = (const int*)d_in[0];
  const int* cols = (const int*)d_in[1];
  const float* vals = (const float*)d_in[2];
  const float* emb = (const float*)d_in[3];
  const float* W = (const float*)d_in[4];
  float* out = (float*)d_out;

  int E = in_sizes[0];
  int N = in_sizes[3] / D;
  int L = in_sizes[4] / (D * D);
  float scl = 1.0f / (float)(L + 1);

  // bucket geometry: bshift=10 -> <=128 buckets for N<=131072 (col packs in 17 bits)
  int bshift = 10;
  int NBUCK = (N + (1 << bshift) - 1) >> bshift;

  // chunking for the partition: NW <= 512 WGs
  int per = 4096;
  while ((E + per - 1) / per > 512) per *= 2;
  int NW = (E + per - 1) / per;

  char* ws = (char*)d_ws;
  size_t off = 0;
  auto take = [&](size_t bytes) -> void* {
    void* p = ws + off;
    off += (bytes + 255) & ~(size_t)255;
    return p;
  };
  unsigned short* xb0 = (unsigned short*)take((size_t)N * D * 2);
  unsigned short* xb1 = (unsigned short*)take((size_t)N * D * 2);
  unsigned short* xb2 = (unsigned short*)take((size_t)N * D * 2);
  unsigned short* xb3 = (unsigned short*)take((size_t)N * D * 2);
  unsigned short* yB  = (unsigned short*)take((size_t)N * D * 2);
  unsigned short* wb  = (unsigned short*)take((size_t)L * D * D * 2);
  float* nrm = (float*)take((size_t)L * N * sizeof(float));
  int* offsets = (int*)take((size_t)(N + 1) * 4);
  int* wghist = (int*)take((size_t)NBUCK_MAX * NW * 4);
  int* wgstart = (int*)take((size_t)NBUCK_MAX * NW * 4);
  int* btot = (int*)take((size_t)NBUCK_MAX * 4);
  int* bstart = (int*)take((size_t)(NBUCK_MAX + 1) * 4);
  uint2* ep = (uint2*)take((size_t)E * 8);
  // gbin aliases xb1: consumed (debin2) strictly before spmm layer 0 writes xb1 (stream-ordered)
  uint2* gbin = (uint2*)xb1;

  // radix partition into buckets, then per-bucket offsets + scatter
  wg_hist<<<NW, 256, 0, stream>>>(rows, wghist, E, NW, per, bshift);
  scan_wg<<<NBUCK, 512, 0, stream>>>(wghist, wgstart, btot, NW);
  scan_buckets<<<1, 128, 0, stream>>>(btot, bstart, NBUCK);
  partition_kernel<<<NW, 256, 0, stream>>>(rows, cols, vals, wgstart, bstart, gbin, E, NW, per, bshift);
  debin2<<<NBUCK, 256, 0, stream>>>(gbin, bstart, offsets, ep, N, E, bshift, NBUCK);

  // fp16 conversions
  int n8x = N * D / 8;
  conv_f16<<<(n8x + 255) / 256, 256, 0, stream>>>(emb, xb0, n8x);
  int n8w = L * D * D / 8;
  conv_f16<<<(n8w + 255) / 256, 256, 0, stream>>>(W, wb, n8w);

  unsigned short* xbufs[4] = {xb0, xb1, xb2, xb3};
  int nrb = (N + 63) / 64;
  for (int l = 0; l < L; ++l) {
    gemm_mfma<<<nrb * 2, 256, 0, stream>>>(xbufs[l], wb + (size_t)l * D * D, yB, N);
    spmm_kernel<<<(N + 3) / 4, 256, 0, stream>>>((const uint4*)yB, offsets, ep, xbufs[l + 1], nrm + (size_t)l * N, N);
  }
  combine_kernel<<<(N + 3) / 4, 256, 0, stream>>>(emb, xb1, xb2, xb3, nrm, out, N, scl);
}

// Round 8
// 393.233 us; speedup vs baseline: 1.8250x; 1.0577x over previous
//
#include <hip/hip_runtime.h>
#include <hip/hip_fp16.h>
#include <math.h>

#define D 128
#define NBUCK_MAX 128
#define BROWS 1024   // rows per bucket (bshift=10); requires N <= 131072 (col packs in 17 bits)

typedef _Float16 f16x8 __attribute__((ext_vector_type(8)));
typedef _Float16 f16x2 __attribute__((ext_vector_type(2)));
typedef __attribute__((ext_vector_type(4))) float f32x4;

static __device__ __forceinline__ unsigned short f2h(float f) {
  __half h = __float2half(f);
  return *reinterpret_cast<unsigned short*>(&h);
}
static __device__ __forceinline__ float hlo(unsigned u) {
  __half2 h = *reinterpret_cast<__half2*>(&u);
  return __low2float(h);
}
static __device__ __forceinline__ float hhi(unsigned u) {
  __half2 h = *reinterpret_cast<__half2*>(&u);
  return __high2float(h);
}
static __device__ __forceinline__ __half2 u2h(unsigned u) { return *reinterpret_cast<__half2*>(&u); }
static __device__ __forceinline__ unsigned h2u(__half2 h) { return *reinterpret_cast<unsigned*>(&h); }
static __device__ __forceinline__ unsigned relu2(unsigned u) {
  f16x2 v = *reinterpret_cast<f16x2*>(&u);
  v = __builtin_elementwise_max(v, (f16x2)(_Float16)0.0f);
  return *reinterpret_cast<unsigned*>(&v);
}

// ---- radix partition by bucket (row >> bshift), WG-private histograms ----
__global__ __launch_bounds__(256) void wg_hist(const int* __restrict__ rows, int* __restrict__ wghist,
                                               int E, int NW, int per, int bshift) {
  __shared__ int cnt[NBUCK_MAX];
  int tid = threadIdx.x, w = blockIdx.x;
  if (tid < NBUCK_MAX) cnt[tid] = 0;
  __syncthreads();
  int base = w * per;
  int end = base + per; if (end > E) end = E;
  for (int e = base + tid; e < end; e += 256) atomicAdd(&cnt[rows[e] >> bshift], 1);
  __syncthreads();
  if (tid < NBUCK_MAX) wghist[tid * NW + w] = cnt[tid];
}

__global__ __launch_bounds__(512) void scan_wg(const int* __restrict__ wghist, int* __restrict__ wgstart,
                                               int* __restrict__ btot, int NW) {
  int b = blockIdx.x, t = threadIdx.x;
  __shared__ int s[512];
  int v = (t < NW) ? wghist[b * NW + t] : 0;
  s[t] = v;
  __syncthreads();
  for (int d = 1; d < 512; d <<= 1) {
    int x = (t >= d) ? s[t - d] : 0;
    __syncthreads();
    s[t] += x;
    __syncthreads();
  }
  if (t < NW) wgstart[b * NW + t] = s[t] - v;
  if (t == 511) btot[b] = s[511];
}

__global__ __launch_bounds__(128) void scan_buckets(const int* __restrict__ btot, int* __restrict__ bstart, int NBUCK) {
  int t = threadIdx.x;
  __shared__ int s[128];
  int v = (t < NBUCK) ? btot[t] : 0;
  s[t] = v;
  __syncthreads();
  for (int d = 1; d < 128; d <<= 1) {
    int x = (t >= d) ? s[t - d] : 0;
    __syncthreads();
    s[t] += x;
    __syncthreads();
  }
  if (t < NBUCK) bstart[t] = s[t] - v;
  if (t == 127) bstart[NBUCK] = s[127];
}

__global__ __launch_bounds__(256) void partition_kernel(const int* __restrict__ rows, const int* __restrict__ cols,
                                                        const float* __restrict__ vals, const int* __restrict__ wgstart,
                                                        const int* __restrict__ bstart,
                                                        uint2* __restrict__ gbin, int E, int NW, int per, int bshift) {
  __shared__ int cur[NBUCK_MAX];
  int tid = threadIdx.x, w = blockIdx.x;
  if (tid < NBUCK_MAX) cur[tid] = bstart[tid] + wgstart[tid * NW + w];
  __syncthreads();
  unsigned rmask = (1u << bshift) - 1u;
  int base = w * per;
  int end = base + per; if (end > E) end = E;
  for (int e = base + tid; e < end; e += 256) {
    unsigned r = (unsigned)rows[e];
    int b = r >> bshift;
    int pos = atomicAdd(&cur[b], 1);
    gbin[pos] = make_uint2(((r & rmask) << 17) | (unsigned)cols[e], __float_as_uint(vals[e]));
  }
}

// per-bucket: LDS row-histogram + scan -> row offsets; scatter into final CSR ep
// ep entry: .x = Y-row byte offset (col*256), .y = val as packed half2 (h | h<<16)
__global__ __launch_bounds__(256) void debin2(const uint2* __restrict__ gbin, const int* __restrict__ bstart,
                                              int* __restrict__ offsets, uint2* __restrict__ ep,
                                              int N, int E, int bshift, int NBUCK) {
  __shared__ int cnt[BROWS];
  __shared__ int sblk[256];
  int b = blockIdx.x, t = threadIdx.x;
  int r0 = b << bshift;
  int r1 = r0 + BROWS; if (r1 > N) r1 = N;
  int nr = r1 - r0;
  int s0 = bstart[b], e0 = bstart[b + 1];
#pragma unroll
  for (int q = 0; q < 4; ++q) cnt[t * 4 + q] = 0;
  __syncthreads();
  for (int i = s0 + t; i < e0; i += 256) atomicAdd(&cnt[gbin[i].x >> 17], 1);
  __syncthreads();
  int c[4]; int tsum = 0;
#pragma unroll
  for (int q = 0; q < 4; ++q) { c[q] = cnt[4 * t + q]; tsum += c[q]; }
  sblk[t] = tsum;
  __syncthreads();
  for (int d = 1; d < 256; d <<= 1) {
    int x = (t >= d) ? sblk[t - d] : 0;
    __syncthreads();
    sblk[t] += x;
    __syncthreads();
  }
  int run = s0 + sblk[t] - tsum;
#pragma unroll
  for (int q = 0; q < 4; ++q) {
    int j = 4 * t + q;
    if (j < nr) offsets[r0 + j] = run;
    cnt[j] = run;   // reuse as absolute cursor
    run += c[q];
  }
  __syncthreads();
  for (int i = s0 + t; i < e0; i += 256) {
    uint2 en = gbin[i];
    int lr = (int)(en.x >> 17);
    int pos = atomicAdd(&cnt[lr], 1);
    unsigned short h = f2h(__uint_as_float(en.y));
    ep[pos] = make_uint2((en.x & 0x1FFFFu) << 8, ((unsigned)h << 16) | (unsigned)h);
  }
  if (b == NBUCK - 1 && t == 0) offsets[N] = E;
}

// ---------------- fp32 -> fp16 converter ----------------
__global__ __launch_bounds__(256) void conv_f16(const float* __restrict__ in, unsigned short* __restrict__ outv, int n8) {
  int t = blockIdx.x * 256 + threadIdx.x;
  if (t >= n8) return;
  size_t base = (size_t)t * 8;
  float4 a = *(const float4*)&in[base];
  float4 b = *(const float4*)&in[base + 4];
  ushort4 o0, o1;
  o0.x = f2h(a.x); o0.y = f2h(a.y); o0.z = f2h(a.z); o0.w = f2h(a.w);
  o1.x = f2h(b.x); o1.y = f2h(b.y); o1.z = f2h(b.z); o1.w = f2h(b.w);
  *(ushort4*)&outv[base] = o0;
  *(ushort4*)&outv[base + 4] = o1;
}

// ---------------- GEMM (MFMA f16): Y[r][c] = sum_k X[r][k] * Wl[c][k] ----------------
__global__ __launch_bounds__(256) void gemm_mfma(const unsigned short* __restrict__ xb,
                                                 const unsigned short* __restrict__ wb,
                                                 unsigned short* __restrict__ Y, int N) {
  int wave = threadIdx.x >> 6, lane = threadIdx.x & 63;
  int bid = blockIdx.x;
  int ch = bid & 1, rblk = bid >> 1;
  int r0 = rblk * 64 + wave * 16;
  if (r0 >= N) return;
  int c0 = ch * 64;
  int lr = lane & 15, lk = lane >> 4;
  const unsigned short* xrow = xb + (size_t)(r0 + lr) * D + lk * 8;
  f16x8 xf[4];
#pragma unroll
  for (int s = 0; s < 4; ++s) xf[s] = *(const f16x8*)(xrow + 32 * s);
  f32x4 acc[4];
#pragma unroll
  for (int mt = 0; mt < 4; ++mt) acc[mt] = (f32x4){0.f, 0.f, 0.f, 0.f};
#pragma unroll
  for (int mt = 0; mt < 4; ++mt) {
    const unsigned short* wrow = wb + (size_t)(c0 + mt * 16 + lr) * D + lk * 8;
#pragma unroll
    for (int s = 0; s < 4; ++s) {
      f16x8 wf = *(const f16x8*)(wrow + 32 * s);
      acc[mt] = __builtin_amdgcn_mfma_f32_16x16x32_f16(wf, xf[s], acc[mt], 0, 0, 0);
    }
  }
#pragma unroll
  for (int mt = 0; mt < 4; ++mt) {
    ushort4 o;
    o.x = f2h(acc[mt][0]); o.y = f2h(acc[mt][1]); o.z = f2h(acc[mt][2]); o.w = f2h(acc[mt][3]);
    *(ushort4*)&Y[(size_t)(r0 + lr) * D + c0 + mt * 16 + lk * 4] = o;
  }
}

// ---------------- SpMM + ReLU -> fp16 Xn + row norm (packed half2 math) ----------------
__global__ __launch_bounds__(256) void spmm_kernel(const char* __restrict__ Yb, const int* __restrict__ offs,
                                                   const uint2* __restrict__ ep,
                                                   unsigned* __restrict__ Xn, float* __restrict__ nrm, int N) {
  int w = threadIdx.x >> 6, lane = threadIdx.x & 63;
  int r = blockIdx.x * 4 + w;
  if (r >= N) return;
  int g = lane >> 4, l = lane & 15;
  int s = offs[r], e = offs[r + 1];
  unsigned acc[4] = {0u, 0u, 0u, 0u};   // 4x packed half2 (+0 bits)
  int loff = l * 16;
  for (int base = s; base < e; base += 16) {
    uint2 ed[4];
#pragma unroll
    for (int q = 0; q < 4; ++q) {
      int i = base + 4 * q + g;
      ed[q] = (i < e) ? ep[i] : make_uint2(0u, 0u);
    }
    uint4 yv[4];
#pragma unroll
    for (int q = 0; q < 4; ++q) yv[q] = *(const uint4*)(Yb + (size_t)(ed[q].x + loff));
#pragma unroll
    for (int q = 0; q < 4; ++q) {
      __half2 f2 = u2h(ed[q].y);
      unsigned uu[4] = {yv[q].x, yv[q].y, yv[q].z, yv[q].w};
#pragma unroll
      for (int k = 0; k < 4; ++k) {
        __half2 a2 = __hfma2(u2h(uu[k]), f2, u2h(acc[k]));
        acc[k] = h2u(a2);
      }
    }
  }
  // cross-group reduce (f16 packed), then ReLU
#pragma unroll
  for (int k = 0; k < 4; ++k) {
    unsigned a = acc[k];
    unsigned b = (unsigned)__shfl_xor((int)a, 16);
    a = h2u(__hadd2(u2h(a), u2h(b)));
    b = (unsigned)__shfl_xor((int)a, 32);
    a = relu2(h2u(__hadd2(u2h(a), u2h(b))));
    acc[k] = a;
  }
  // row norm (fp32 squares)
  float ss = 0.f;
#pragma unroll
  for (int k = 0; k < 4; ++k) {
    float lo = hlo(acc[k]), hi = hhi(acc[k]);
    ss = fmaf(lo, lo, ss);
    ss = fmaf(hi, hi, ss);
  }
  ss += __shfl_xor(ss, 1);
  ss += __shfl_xor(ss, 2);
  ss += __shfl_xor(ss, 4);
  ss += __shfl_xor(ss, 8);
  if (lane == 0) nrm[r] = sqrtf(ss);
  if (g == 0) {
    uint4 o = make_uint4(acc[0], acc[1], acc[2], acc[3]);
    *(uint4*)&Xn[(size_t)r * (D / 2) + l * 4] = o;
  }
}

// ---------------- final combine: out = scl*( x0/||x0|| + sum_l x_l / max(nrm_l,eps) ) ----------------
__global__ __launch_bounds__(256) void combine_kernel(const unsigned short* __restrict__ x0,
                                                      const unsigned short* __restrict__ x1,
                                                      const unsigned short* __restrict__ x2,
                                                      const unsigned short* __restrict__ x3,
                                                      const float* __restrict__ nrm,
                                                      float* __restrict__ out, int N, float scl) {
  int w = threadIdx.x >> 6, lane = threadIdx.x & 63;
  int r = blockIdx.x * 4 + w;
  if (r >= N) return;
  size_t p = (size_t)r * D + 2 * lane;
  unsigned a0 = *(const unsigned*)&x0[p];
  float v0 = hlo(a0), v1 = hhi(a0);
  float ss = v0 * v0 + v1 * v1;
  for (int off = 32; off; off >>= 1) ss += __shfl_xor(ss, off);
  float s0 = scl / fmaxf(sqrtf(ss), 1e-12f);
  float i1 = scl / fmaxf(nrm[r], 1e-12f);
  float i2 = scl / fmaxf(nrm[N + r], 1e-12f);
  float i3 = scl / fmaxf(nrm[2 * N + r], 1e-12f);
  unsigned a1 = *(const unsigned*)&x1[p];
  unsigned a2 = *(const unsigned*)&x2[p];
  unsigned a3 = *(const unsigned*)&x3[p];
  float2 o;
  o.x = s0 * v0 + i1 * hlo(a1) + i2 * hlo(a2) + i3 * hlo(a3);
  o.y = s0 * v1 + i1 * hhi(a1) + i2 * hhi(a2) + i3 * hhi(a3);
  *(float2*)&out[p] = o;
}

// ---------------- launch ----------------
extern "C" void kernel_launch(void* const* d_in, const int* in_sizes, int n_in,
                              void* d_out, int out_size, void* d_ws, size_t ws_size,
                              hipStream_t stream) {
  const int* rows = (const int*)d_in[0];
  const int* cols = (const int*)d_in[1];
  const float* vals = (const float*)d_in[2];
  const float* emb = (const float*)d_in[3];
  const float* W = (const float*)d_in[4];
  float* out = (float*)d_out;

  int E = in_sizes[0];
  int N = in_sizes[3] / D;
  int L = in_sizes[4] / (D * D);
  float scl = 1.0f / (float)(L + 1);

  int bshift = 10;
  int NBUCK = (N + (1 << bshift) - 1) >> bshift;

  int per = 4096;
  while ((E + per - 1) / per > 512) per *= 2;
  int NW = (E + per - 1) / per;

  char* ws = (char*)d_ws;
  size_t off = 0;
  auto take = [&](size_t bytes) -> void* {
    void* p = ws + off;
    off += (bytes + 255) & ~(size_t)255;
    return p;
  };
  unsigned short* xb0 = (unsigned short*)take((size_t)N * D * 2);
  unsigned short* xb1 = (unsigned short*)take((size_t)N * D * 2);
  unsigned short* xb2 = (unsigned short*)take((size_t)N * D * 2);
  unsigned short* xb3 = (unsigned short*)take((size_t)N * D * 2);
  unsigned short* yB  = (unsigned short*)take((size_t)N * D * 2);
  unsigned short* wb  = (unsigned short*)take((size_t)L * D * D * 2);
  float* nrm = (float*)take((size_t)L * N * sizeof(float));
  int* offsets = (int*)take((size_t)(N + 1) * 4);
  int* wghist = (int*)take((size_t)NBUCK_MAX * NW * 4);
  int* wgstart = (int*)take((size_t)NBUCK_MAX * NW * 4);
  int* btot = (int*)take((size_t)NBUCK_MAX * 4);
  int* bstart = (int*)take((size_t)(NBUCK_MAX + 1) * 4);
  uint2* ep = (uint2*)take((size_t)E * 8);
  // gbin aliases xb1: consumed (debin2) strictly before spmm layer 0 writes xb1 (stream-ordered)
  uint2* gbin = (uint2*)xb1;

  // radix partition into buckets, then per-bucket offsets + scatter
  wg_hist<<<NW, 256, 0, stream>>>(rows, wghist, E, NW, per, bshift);
  scan_wg<<<NBUCK, 512, 0, stream>>>(wghist, wgstart, btot, NW);
  scan_buckets<<<1, 128, 0, stream>>>(btot, bstart, NBUCK);
  partition_kernel<<<NW, 256, 0, stream>>>(rows, cols, vals, wgstart, bstart, gbin, E, NW, per, bshift);
  debin2<<<NBUCK, 256, 0, stream>>>(gbin, bstart, offsets, ep, N, E, bshift, NBUCK);

  // fp16 conversions
  int n8x = N * D / 8;
  conv_f16<<<(n8x + 255) / 256, 256, 0, stream>>>(emb, xb0, n8x);
  int n8w = L * D * D / 8;
  conv_f16<<<(n8w + 255) / 256, 256, 0, stream>>>(W, wb, n8w);

  unsigned short* xbufs[4] = {xb0, xb1, xb2, xb3};
  int nrb = (N + 63) / 64;
  for (int l = 0; l < L; ++l) {
    gemm_mfma<<<nrb * 2, 256, 0, stream>>>(xbufs[l], wb + (size_t)l * D * D, yB, N);
    spmm_kernel<<<(N + 3) / 4, 256, 0, stream>>>((const char*)yB, offsets, ep,
                                                 (unsigned*)xbufs[l + 1], nrm + (size_t)l * N, N);
  }
  combine_kernel<<<(N + 3) / 4, 256, 0, stream>>>(xb0, xb1, xb2, xb3, nrm, out, N, scl);
}

// Round 9
// 391.753 us; speedup vs baseline: 1.8319x; 1.0038x over previous
//
#include <hip/hip_runtime.h>
#include <hip/hip_fp16.h>
#include <math.h>

#define D 128
#define NBUCK_MAX 128
#define BROWS 1024   // rows per bucket (bshift=10); requires N <= 131072 (col packs in 17 bits)

typedef _Float16 f16x8 __attribute__((ext_vector_type(8)));
typedef _Float16 f16x2 __attribute__((ext_vector_type(2)));
typedef __attribute__((ext_vector_type(4))) float f32x4;

static __device__ __forceinline__ unsigned short f2h(float f) {
  __half h = __float2half(f);
  return *reinterpret_cast<unsigned short*>(&h);
}
static __device__ __forceinline__ float hlo(unsigned u) {
  __half2 h = *reinterpret_cast<__half2*>(&u);
  return __low2float(h);
}
static __device__ __forceinline__ float hhi(unsigned u) {
  __half2 h = *reinterpret_cast<__half2*>(&u);
  return __high2float(h);
}
static __device__ __forceinline__ __half2 u2h(unsigned u) { return *reinterpret_cast<__half2*>(&u); }
static __device__ __forceinline__ unsigned h2u(__half2 h) { return *reinterpret_cast<unsigned*>(&h); }
static __device__ __forceinline__ unsigned relu2(unsigned u) {
  f16x2 v = *reinterpret_cast<f16x2*>(&u);
  v = __builtin_elementwise_max(v, (f16x2)(_Float16)0.0f);
  return *reinterpret_cast<unsigned*>(&v);
}

// ---- radix partition by bucket (row >> bshift), WG-private histograms ----
__global__ __launch_bounds__(256) void wg_hist(const int* __restrict__ rows, int* __restrict__ wghist,
                                               int E, int NW, int per, int bshift) {
  __shared__ int cnt[NBUCK_MAX];
  int tid = threadIdx.x, w = blockIdx.x;
  if (tid < NBUCK_MAX) cnt[tid] = 0;
  __syncthreads();
  int base = w * per;
  int end = base + per; if (end > E) end = E;
  for (int e = base + tid; e < end; e += 256) atomicAdd(&cnt[rows[e] >> bshift], 1);
  __syncthreads();
  if (tid < NBUCK_MAX) wghist[tid * NW + w] = cnt[tid];
}

__global__ __launch_bounds__(512) void scan_wg(const int* __restrict__ wghist, int* __restrict__ wgstart,
                                               int* __restrict__ btot, int NW) {
  int b = blockIdx.x, t = threadIdx.x;
  __shared__ int s[512];
  int v = (t < NW) ? wghist[b * NW + t] : 0;
  s[t] = v;
  __syncthreads();
  for (int d = 1; d < 512; d <<= 1) {
    int x = (t >= d) ? s[t - d] : 0;
    __syncthreads();
    s[t] += x;
    __syncthreads();
  }
  if (t < NW) wgstart[b * NW + t] = s[t] - v;
  if (t == 511) btot[b] = s[511];
}

__global__ __launch_bounds__(128) void scan_buckets(const int* __restrict__ btot, int* __restrict__ bstart, int NBUCK) {
  int t = threadIdx.x;
  __shared__ int s[128];
  int v = (t < NBUCK) ? btot[t] : 0;
  s[t] = v;
  __syncthreads();
  for (int d = 1; d < 128; d <<= 1) {
    int x = (t >= d) ? s[t - d] : 0;
    __syncthreads();
    s[t] += x;
    __syncthreads();
  }
  if (t < NBUCK) bstart[t] = s[t] - v;
  if (t == 127) bstart[NBUCK] = s[127];
}

__global__ __launch_bounds__(256) void partition_kernel(const int* __restrict__ rows, const int* __restrict__ cols,
                                                        const float* __restrict__ vals, const int* __restrict__ wgstart,
                                                        const int* __restrict__ bstart,
                                                        uint2* __restrict__ gbin, int E, int NW, int per, int bshift) {
  __shared__ int cur[NBUCK_MAX];
  int tid = threadIdx.x, w = blockIdx.x;
  if (tid < NBUCK_MAX) cur[tid] = bstart[tid] + wgstart[tid * NW + w];
  __syncthreads();
  unsigned rmask = (1u << bshift) - 1u;
  int base = w * per;
  int end = base + per; if (end > E) end = E;
  for (int e = base + tid; e < end; e += 256) {
    unsigned r = (unsigned)rows[e];
    int b = r >> bshift;
    int pos = atomicAdd(&cur[b], 1);
    gbin[pos] = make_uint2(((r & rmask) << 17) | (unsigned)cols[e], __float_as_uint(vals[e]));
  }
}

// per-bucket: LDS row-histogram + scan -> row offsets; scatter into final CSR ep
// ep entry: .x = Y-row byte offset (col*256), .y = val as packed half2 (h | h<<16)
__global__ __launch_bounds__(256) void debin2(const uint2* __restrict__ gbin, const int* __restrict__ bstart,
                                              int* __restrict__ offsets, uint2* __restrict__ ep,
                                              int N, int E, int bshift, int NBUCK) {
  __shared__ int cnt[BROWS];
  __shared__ int sblk[256];
  int b = blockIdx.x, t = threadIdx.x;
  int r0 = b << bshift;
  int r1 = r0 + BROWS; if (r1 > N) r1 = N;
  int nr = r1 - r0;
  int s0 = bstart[b], e0 = bstart[b + 1];
#pragma unroll
  for (int q = 0; q < 4; ++q) cnt[t * 4 + q] = 0;
  __syncthreads();
  for (int i = s0 + t; i < e0; i += 256) atomicAdd(&cnt[gbin[i].x >> 17], 1);
  __syncthreads();
  int c[4]; int tsum = 0;
#pragma unroll
  for (int q = 0; q < 4; ++q) { c[q] = cnt[4 * t + q]; tsum += c[q]; }
  sblk[t] = tsum;
  __syncthreads();
  for (int d = 1; d < 256; d <<= 1) {
    int x = (t >= d) ? sblk[t - d] : 0;
    __syncthreads();
    sblk[t] += x;
    __syncthreads();
  }
  int run = s0 + sblk[t] - tsum;
#pragma unroll
  for (int q = 0; q < 4; ++q) {
    int j = 4 * t + q;
    if (j < nr) offsets[r0 + j] = run;
    cnt[j] = run;   // reuse as absolute cursor
    run += c[q];
  }
  __syncthreads();
  for (int i = s0 + t; i < e0; i += 256) {
    uint2 en = gbin[i];
    int lr = (int)(en.x >> 17);
    int pos = atomicAdd(&cnt[lr], 1);
    unsigned short h = f2h(__uint_as_float(en.y));
    ep[pos] = make_uint2((en.x & 0x1FFFFu) << 8, ((unsigned)h << 16) | (unsigned)h);
  }
  if (b == NBUCK - 1 && t == 0) offsets[N] = E;
}

// ---------------- fp32 -> fp16 converter ----------------
__global__ __launch_bounds__(256) void conv_f16(const float* __restrict__ in, unsigned short* __restrict__ outv, int n8) {
  int t = blockIdx.x * 256 + threadIdx.x;
  if (t >= n8) return;
  size_t base = (size_t)t * 8;
  float4 a = *(const float4*)&in[base];
  float4 b = *(const float4*)&in[base + 4];
  ushort4 o0, o1;
  o0.x = f2h(a.x); o0.y = f2h(a.y); o0.z = f2h(a.z); o0.w = f2h(a.w);
  o1.x = f2h(b.x); o1.y = f2h(b.y); o1.z = f2h(b.z); o1.w = f2h(b.w);
  *(ushort4*)&outv[base] = o0;
  *(ushort4*)&outv[base + 4] = o1;
}

// ---------------- GEMM (MFMA f16): Y[r][c] = sum_k X[r][k] * Wl[c][k] ----------------
// block = 4 waves; each wave: 16 rows x all 128 cols (8 col-tiles of 16)
__global__ __launch_bounds__(256) void gemm_mfma(const unsigned short* __restrict__ xb,
                                                 const unsigned short* __restrict__ wb,
                                                 unsigned short* __restrict__ Y, int N) {
  int wave = threadIdx.x >> 6, lane = threadIdx.x & 63;
  int r0 = blockIdx.x * 64 + wave * 16;
  if (r0 >= N) return;
  int lr = lane & 15, lk = lane >> 4;
  const unsigned short* xrow = xb + (size_t)(r0 + lr) * D + lk * 8;
  f16x8 xf[4];
#pragma unroll
  for (int s = 0; s < 4; ++s) xf[s] = *(const f16x8*)(xrow + 32 * s);
  f32x4 acc[8];
#pragma unroll
  for (int mt = 0; mt < 8; ++mt) acc[mt] = (f32x4){0.f, 0.f, 0.f, 0.f};
#pragma unroll
  for (int mt = 0; mt < 8; ++mt) {
    const unsigned short* wrow = wb + (size_t)(mt * 16 + lr) * D + lk * 8;
#pragma unroll
    for (int s = 0; s < 4; ++s) {
      f16x8 wf = *(const f16x8*)(wrow + 32 * s);
      acc[mt] = __builtin_amdgcn_mfma_f32_16x16x32_f16(wf, xf[s], acc[mt], 0, 0, 0);
    }
  }
#pragma unroll
  for (int mt = 0; mt < 8; ++mt) {
    ushort4 o;
    o.x = f2h(acc[mt][0]); o.y = f2h(acc[mt][1]); o.z = f2h(acc[mt][2]); o.w = f2h(acc[mt][3]);
    *(ushort4*)&Y[(size_t)(r0 + lr) * D + mt * 16 + lk * 4] = o;
  }
}

// ---------------- SpMM + ReLU -> fp16 Xn + row norm (packed half2, 32 edges in flight) ----------------
__global__ __launch_bounds__(256) void spmm_kernel(const char* __restrict__ Yb, const int* __restrict__ offs,
                                                   const uint2* __restrict__ ep,
                                                   unsigned* __restrict__ Xn, float* __restrict__ nrm, int N) {
  int w = threadIdx.x >> 6, lane = threadIdx.x & 63;
  int r = blockIdx.x * 4 + w;
  if (r >= N) return;
  int g = lane >> 4, l = lane & 15;
  int s = offs[r], e = offs[r + 1];
  unsigned acc[4] = {0u, 0u, 0u, 0u};   // 4x packed half2
  int loff = l * 16;
  for (int base = s; base < e; base += 32) {
    uint2 ed[8];
#pragma unroll
    for (int q = 0; q < 8; ++q) {
      int i = base + 4 * q + g;
      ed[q] = (i < e) ? ep[i] : make_uint2(0u, 0u);
    }
    uint4 yv[8];
#pragma unroll
    for (int q = 0; q < 8; ++q) yv[q] = *(const uint4*)(Yb + (size_t)(ed[q].x + loff));
#pragma unroll
    for (int q = 0; q < 8; ++q) {
      __half2 f2 = u2h(ed[q].y);
      unsigned uu[4] = {yv[q].x, yv[q].y, yv[q].z, yv[q].w};
#pragma unroll
      for (int k = 0; k < 4; ++k) {
        __half2 a2 = __hfma2(u2h(uu[k]), f2, u2h(acc[k]));
        acc[k] = h2u(a2);
      }
    }
  }
  // cross-group reduce (f16 packed), then ReLU
#pragma unroll
  for (int k = 0; k < 4; ++k) {
    unsigned a = acc[k];
    unsigned b = (unsigned)__shfl_xor((int)a, 16);
    a = h2u(__hadd2(u2h(a), u2h(b)));
    b = (unsigned)__shfl_xor((int)a, 32);
    a = relu2(h2u(__hadd2(u2h(a), u2h(b))));
    acc[k] = a;
  }
  // row norm (fp32 squares)
  float ss = 0.f;
#pragma unroll
  for (int k = 0; k < 4; ++k) {
    float lo = hlo(acc[k]), hi = hhi(acc[k]);
    ss = fmaf(lo, lo, ss);
    ss = fmaf(hi, hi, ss);
  }
  ss += __shfl_xor(ss, 1);
  ss += __shfl_xor(ss, 2);
  ss += __shfl_xor(ss, 4);
  ss += __shfl_xor(ss, 8);
  if (lane == 0) nrm[r] = sqrtf(ss);
  if (g == 0) {
    uint4 o = make_uint4(acc[0], acc[1], acc[2], acc[3]);
    *(uint4*)&Xn[(size_t)r * (D / 2) + l * 4] = o;
  }
}

// ---------------- final combine: out = scl*( x0/||x0|| + sum_l x_l / max(nrm_l,eps) ) ----------------
__global__ __launch_bounds__(256) void combine_kernel(const unsigned short* __restrict__ x0,
                                                      const unsigned short* __restrict__ x1,
                                                      const unsigned short* __restrict__ x2,
                                                      const unsigned short* __restrict__ x3,
                                                      const float* __restrict__ nrm,
                                                      float* __restrict__ out, int N, float scl) {
  int w = threadIdx.x >> 6, lane = threadIdx.x & 63;
  int r = blockIdx.x * 4 + w;
  if (r >= N) return;
  size_t p = (size_t)r * D + 2 * lane;
  unsigned a0 = *(const unsigned*)&x0[p];
  float v0 = hlo(a0), v1 = hhi(a0);
  float ss = v0 * v0 + v1 * v1;
  for (int off = 32; off; off >>= 1) ss += __shfl_xor(ss, off);
  float s0 = scl / fmaxf(sqrtf(ss), 1e-12f);
  float i1 = scl / fmaxf(nrm[r], 1e-12f);
  float i2 = scl / fmaxf(nrm[N + r], 1e-12f);
  float i3 = scl / fmaxf(nrm[2 * N + r], 1e-12f);
  unsigned a1 = *(const unsigned*)&x1[p];
  unsigned a2 = *(const unsigned*)&x2[p];
  unsigned a3 = *(const unsigned*)&x3[p];
  float2 o;
  o.x = s0 * v0 + i1 * hlo(a1) + i2 * hlo(a2) + i3 * hlo(a3);
  o.y = s0 * v1 + i1 * hhi(a1) + i2 * hhi(a2) + i3 * hhi(a3);
  *(float2*)&out[p] = o;
}

// ---------------- launch ----------------
extern "C" void kernel_launch(void* const* d_in, const int* in_sizes, int n_in,
                              void* d_out, int out_size, void* d_ws, size_t ws_size,
                              hipStream_t stream) {
  const int* rows = (const int*)d_in[0];
  const int* cols = (const int*)d_in[1];
  const float* vals = (const float*)d_in[2];
  const float* emb = (const float*)d_in[3];
  const float* W = (const float*)d_in[4];
  float* out = (float*)d_out;

  int E = in_sizes[0];
  int N = in_sizes[3] / D;
  int L = in_sizes[4] / (D * D);
  float scl = 1.0f / (float)(L + 1);

  int bshift = 10;
  int NBUCK = (N + (1 << bshift) - 1) >> bshift;

  int per = 4096;
  while ((E + per - 1) / per > 512) per *= 2;
  int NW = (E + per - 1) / per;

  char* ws = (char*)d_ws;
  size_t off = 0;
  auto take = [&](size_t bytes) -> void* {
    void* p = ws + off;
    off += (bytes + 255) & ~(size_t)255;
    return p;
  };
  unsigned short* xb0 = (unsigned short*)take((size_t)N * D * 2);
  unsigned short* xb1 = (unsigned short*)take((size_t)N * D * 2);
  unsigned short* xb2 = (unsigned short*)take((size_t)N * D * 2);
  unsigned short* xb3 = (unsigned short*)take((size_t)N * D * 2);
  unsigned short* yB  = (unsigned short*)take((size_t)N * D * 2);
  unsigned short* wb  = (unsigned short*)take((size_t)L * D * D * 2);
  float* nrm = (float*)take((size_t)L * N * sizeof(float));
  int* offsets = (int*)take((size_t)(N + 1) * 4);
  int* wghist = (int*)take((size_t)NBUCK_MAX * NW * 4);
  int* wgstart = (int*)take((size_t)NBUCK_MAX * NW * 4);
  int* btot = (int*)take((size_t)NBUCK_MAX * 4);
  int* bstart = (int*)take((size_t)(NBUCK_MAX + 1) * 4);
  uint2* ep = (uint2*)take((size_t)E * 8);
  // gbin aliases xb1: consumed (debin2) strictly before spmm layer 0 writes xb1 (stream-ordered)
  uint2* gbin = (uint2*)xb1;

  // radix partition into buckets, then per-bucket offsets + scatter
  wg_hist<<<NW, 256, 0, stream>>>(rows, wghist, E, NW, per, bshift);
  scan_wg<<<NBUCK, 512, 0, stream>>>(wghist, wgstart, btot, NW);
  scan_buckets<<<1, 128, 0, stream>>>(btot, bstart, NBUCK);
  partition_kernel<<<NW, 256, 0, stream>>>(rows, cols, vals, wgstart, bstart, gbin, E, NW, per, bshift);
  debin2<<<NBUCK, 256, 0, stream>>>(gbin, bstart, offsets, ep, N, E, bshift, NBUCK);

  // fp16 conversions
  int n8x = N * D / 8;
  conv_f16<<<(n8x + 255) / 256, 256, 0, stream>>>(emb, xb0, n8x);
  int n8w = L * D * D / 8;
  conv_f16<<<(n8w + 255) / 256, 256, 0, stream>>>(W, wb, n8w);

  unsigned short* xbufs[4] = {xb0, xb1, xb2, xb3};
  int nrb = (N + 63) / 64;
  for (int l = 0; l < L; ++l) {
    gemm_mfma<<<nrb, 256, 0, stream>>>(xbufs[l], wb + (size_t)l * D * D, yB, N);
    spmm_kernel<<<(N + 3) / 4, 256, 0, stream>>>((const char*)yB, offsets, ep,
                                                 (unsigned*)xbufs[l + 1], nrm + (size_t)l * N, N);
  }
  combine_kernel<<<(N + 3) / 4, 256, 0, stream>>>(xb0, xb1, xb2, xb3, nrm, out, N, scl);
}